// Round 1
// baseline (311.071 us; speedup 1.0000x reference)
//
#include <hip/hip_runtime.h>
#include <math.h>

#define DIMX 256
#define NFEAT 32
#define BATCH 512
#define HEADS 8
#define DHEAD 32
#define KNN 17
#define QKV_W 768
#define SCALE_F 0.17677669529663687f

// ---------------- Stage A: reprs = mean(x,axis=1) @ W_repr + b_repr; normalize ----------------
__global__ void repr_kernel(const float* __restrict__ x, const float* __restrict__ W_repr,
                            const float* __restrict__ b_repr, float* __restrict__ normed) {
  int b = blockIdx.x, t = threadIdx.x;
  __shared__ float mean_s[DIMX];
  __shared__ float red[DIMX];
  float s = 0.f;
#pragma unroll
  for (int n = 0; n < NFEAT; ++n) s += x[(size_t)(b*NFEAT+n)*DIMX + t];
  mean_s[t] = s * (1.0f/NFEAT);
  __syncthreads();
  float acc = b_repr[t];
  for (int d = 0; d < DIMX; ++d) acc += mean_s[d] * W_repr[d*DIMX + t];
  red[t] = acc*acc;
  __syncthreads();
  for (int off = 128; off > 0; off >>= 1) {
    if (t < off) red[t] += red[t+off];
    __syncthreads();
  }
  normed[b*DIMX + t] = acc / sqrtf(red[0]);
}

// ---------------- Stage B: sim row + top-17 (iterative argmax, ties -> lower index) ----------------
__global__ void simtopk_kernel(const float* __restrict__ normed, int* __restrict__ knn) {
  int i = blockIdx.x, t = threadIdx.x;
  __shared__ float myrow[DIMX];
  __shared__ float sims[BATCH];
  __shared__ float rv[256];
  __shared__ int   ri[256];
  myrow[t] = normed[i*DIMX + t];
  __syncthreads();
#pragma unroll
  for (int jj = 0; jj < 2; ++jj) {
    int j = t + jj*256;
    const float* row = &normed[(size_t)j*DIMX];
    float s = 0.f;
    for (int d = 0; d < DIMX; ++d) s += myrow[d] * row[d];
    sims[j] = s;  // TEMPERATURE = 1
  }
  __syncthreads();
  for (int it = 0; it < KNN; ++it) {
    float v1 = sims[t], v2 = sims[t+256];
    float mv; int mi;
    if (v2 > v1) { mv = v2; mi = t+256; } else { mv = v1; mi = t; }
    rv[t] = mv; ri[t] = mi;
    __syncthreads();
    for (int off = 128; off > 0; off >>= 1) {
      if (t < off) {
        if (rv[t+off] > rv[t] || (rv[t+off] == rv[t] && ri[t+off] < ri[t])) {
          rv[t] = rv[t+off]; ri[t] = ri[t+off];
        }
      }
      __syncthreads();
    }
    if (t == 0) { knn[i*32 + it] = ri[0]; sims[ri[0]] = -INFINITY; }
    __syncthreads();
  }
}

// ---------------- Stage C: qkv = x @ W_qkv  (M=16384, K=256, N=768) ----------------
#define BM 128
#define BN 64
#define BK 16
__global__ void qkv_gemm(const float* __restrict__ A, const float* __restrict__ B,
                         float* __restrict__ C) {
  __shared__ float As[BK][BM];   // transposed tile
  __shared__ float Bs[BK][BN];
  int t = threadIdx.x;
  int tx = t & 15, ty = t >> 4;
  int row0 = blockIdx.x * BM;
  int col0 = blockIdx.y * BN;
  int ar = t >> 1, ac = (t & 1) * 8;
  int br = t >> 4, bc = (t & 15) * 4;
  float acc[8][4] = {};
  for (int k0 = 0; k0 < 256; k0 += BK) {
    float4 a0 = *(const float4*)&A[(size_t)(row0+ar)*256 + k0 + ac];
    float4 a1 = *(const float4*)&A[(size_t)(row0+ar)*256 + k0 + ac + 4];
    As[ac+0][ar] = a0.x; As[ac+1][ar] = a0.y; As[ac+2][ar] = a0.z; As[ac+3][ar] = a0.w;
    As[ac+4][ar] = a1.x; As[ac+5][ar] = a1.y; As[ac+6][ar] = a1.z; As[ac+7][ar] = a1.w;
    *(float4*)&Bs[br][bc] = *(const float4*)&B[(size_t)(k0+br)*QKV_W + col0 + bc];
    __syncthreads();
#pragma unroll
    for (int kk = 0; kk < BK; ++kk) {
      float4 av0 = *(float4*)&As[kk][ty*8];
      float4 av1 = *(float4*)&As[kk][ty*8+4];
      float4 bv  = *(float4*)&Bs[kk][tx*4];
      float a[8] = {av0.x,av0.y,av0.z,av0.w,av1.x,av1.y,av1.z,av1.w};
      float bb[4] = {bv.x,bv.y,bv.z,bv.w};
#pragma unroll
      for (int i = 0; i < 8; ++i)
#pragma unroll
        for (int j = 0; j < 4; ++j) acc[i][j] += a[i]*bb[j];
    }
    __syncthreads();
  }
#pragma unroll
  for (int i = 0; i < 8; ++i) {
    float4 o = {acc[i][0], acc[i][1], acc[i][2], acc[i][3]};
    *(float4*)&C[(size_t)(row0+ty*8+i)*QKV_W + col0 + tx*4] = o;
  }
}

// ---------------- Stage D: 17-neighbor attention + fused out-projection ----------------
__global__ void attn_kernel(const float* __restrict__ qkv, const int* __restrict__ knn,
                            const float* __restrict__ W_out, const float* __restrict__ b_out,
                            float* __restrict__ out) {
  int b = blockIdx.x, t = threadIdx.x;
  __shared__ float out_rows[NFEAT][DIMX];  // 32 KB
  __shared__ float q_row[DIMX];
  __shared__ float sc[KNN][HEADS];
  __shared__ int idxs[KNN];
  if (t < KNN) idxs[t] = knn[b*32 + t];
  __syncthreads();
  for (int n = 0; n < NFEAT; ++n) {
    q_row[t] = qkv[(size_t)(b*NFEAT+n)*QKV_W + t];
    __syncthreads();
    if (t < KNN*HEADS) {
      int j = t >> 3, h = t & 7;
      const float* krow = &qkv[(size_t)(idxs[j]*NFEAT+n)*QKV_W + 256 + h*DHEAD];
      float s = 0.f;
#pragma unroll
      for (int d = 0; d < DHEAD; ++d) s += q_row[h*DHEAD+d] * krow[d];
      sc[j][h] = s * SCALE_F;
    }
    __syncthreads();
    if (t < HEADS) {
      float m = -INFINITY;
#pragma unroll
      for (int j = 0; j < KNN; ++j) m = fmaxf(m, sc[j][t]);
      float sum = 0.f;
#pragma unroll
      for (int j = 0; j < KNN; ++j) { float e = expf(sc[j][t] - m); sc[j][t] = e; sum += e; }
      float inv = 1.0f / sum;
#pragma unroll
      for (int j = 0; j < KNN; ++j) sc[j][t] *= inv;
    }
    __syncthreads();
    {
      int h = t >> 5;
      float acc = 0.f;
#pragma unroll
      for (int j = 0; j < KNN; ++j)
        acc += sc[j][h] * qkv[(size_t)(idxs[j]*NFEAT+n)*QKV_W + 512 + t];
      out_rows[n][t] = acc;
    }
    __syncthreads();
  }
  // fused out-projection: [32,256] @ [256,256] + b_out
  float acc[NFEAT];
  float bo = b_out[t];
#pragma unroll
  for (int r = 0; r < NFEAT; ++r) acc[r] = bo;
  for (int d = 0; d < DIMX; ++d) {
    float w = W_out[d*DIMX + t];
#pragma unroll
    for (int r = 0; r < NFEAT; ++r) acc[r] += out_rows[r][d] * w;
  }
#pragma unroll
  for (int r = 0; r < NFEAT; ++r) out[(size_t)(b*NFEAT+r)*DIMX + t] = acc[r];
}

extern "C" void kernel_launch(void* const* d_in, const int* in_sizes, int n_in,
                              void* d_out, int out_size, void* d_ws, size_t ws_size,
                              hipStream_t stream) {
  const float* x      = (const float*)d_in[0];
  const float* W_qkv  = (const float*)d_in[1];
  const float* W_out  = (const float*)d_in[2];
  const float* b_out  = (const float*)d_in[3];
  const float* W_repr = (const float*)d_in[4];
  const float* b_repr = (const float*)d_in[5];
  float* out = (float*)d_out;

  float* qkv    = (float*)d_ws;                          // 16384*768 f32 = 50.3 MB
  float* normed = qkv + (size_t)16384*QKV_W;             // 512*256 f32
  int*   knn    = (int*)(normed + (size_t)BATCH*DIMX);   // 512*32 int

  repr_kernel<<<BATCH, 256, 0, stream>>>(x, W_repr, b_repr, normed);
  simtopk_kernel<<<BATCH, 256, 0, stream>>>(normed, knn);
  qkv_gemm<<<dim3(16384/BM, QKV_W/BN), 256, 0, stream>>>(x, W_qkv, qkv);
  attn_kernel<<<BATCH, 256, 0, stream>>>(qkv, knn, W_out, b_out, out);
}